// Round 10
// baseline (3412.257 us; speedup 1.0000x reference)
//
#include <hip/hip_runtime.h>
#include <hip/hip_bf16.h>

// RNN1DGeneral, barrier-free producer/consumer convoys:
//   16 blocks x 16 batches, 512 threads = 8 waves. NO __syncthreads in the
//   main loop. Waves 0-3 (L0 convoy): h0[t]=elu(h0[t-1]@W0)+R[x[t-1]],
//   t=1..4095. Waves 4-7 (L1 convoy): h1[u]=elu(h1[u-1]@W1)+h0[u], u=1..4095,
//   + logit MFMA on h1[u-1] (u=1..4096). Each wave owns 32 cols.
//   Sync: per-wave LDS flags (= last completed step), acquire-poll peers
//   (>= t-1), cross-convoy: L1 waits flag0 >= u; L0 waits flag1 >= t-3
//   (depth-4 h ring backpressure). Convoy skew <= 1 proven by flag waits;
//   all ring slot reuses checked race-free. SIMD k hosts wave k (L0) and
//   k+4 (L1) at independent phases -> LDS/MFMA/VALU pipes overlap.
//   MFMA D[col][batch]: A = W (static regs), B = h (swizzled ds_read_b128),
//   writes via v_cvt_pk_bf16_f32 + ds_write_b64. Softplus consumer rotates
//   across L1 waves by s mod 4.

#define L_LEN 4096
#define HID   128
#define NB    16
#define TPB   512
#define WPITCH 129

typedef float f32x4 __attribute__((ext_vector_type(4)));
typedef short s16x8 __attribute__((ext_vector_type(8)));

#define MFMA16(A_, B_, C_) __builtin_amdgcn_mfma_f32_16x16x32_bf16((A_), (B_), (C_), 0, 0, 0)

__device__ __forceinline__ float eluf(float v) { return v > 0.f ? v : (__expf(v) - 1.f); }
__device__ __forceinline__ unsigned cvtpk(float lo, float hi) {
    unsigned r;
    asm("v_cvt_pk_bf16_f32 %0, %1, %2" : "=v"(r) : "v"(lo), "v"(hi));
    return r;
}
__device__ __forceinline__ unsigned short f2bf(float v) {
    union { __hip_bfloat16 b; unsigned short u; } cv;
    cv.b = __float2bfloat16(v);
    return cv.u;
}

// wait until flags[i] >= target for all i != skip (skip=-1: all)
__device__ __forceinline__ void wait_ge(int* f, int skip, int target) {
    if (target <= 0) return;
    for (;;) {
        int ok = 1;
        #pragma unroll
        for (int i = 0; i < 4; ++i) {
            if (i == skip) continue;
            ok &= (__hip_atomic_load(&f[i], __ATOMIC_ACQUIRE,
                                     __HIP_MEMORY_SCOPE_WORKGROUP) >= target);
        }
        if (ok) break;
        __builtin_amdgcn_s_sleep(1);
    }
    __builtin_amdgcn_sched_barrier(0);
}
__device__ __forceinline__ void post(int* f, int v) {
    asm volatile("s_waitcnt lgkmcnt(0)" ::: "memory");
    __hip_atomic_store(f, v, __ATOMIC_RELEASE, __HIP_MEMORY_SCOPE_WORKGROUP);
}

__global__ __launch_bounds__(TPB, 1)
void rnn_async_kernel(const int*   __restrict__ x,
                      const float* __restrict__ W_in,
                      const float* __restrict__ W_c,
                      const float* __restrict__ W_out,
                      const float* __restrict__ b_out,
                      float* __restrict__ out)
{
    __shared__ __align__(16) unsigned short hAf[4][2][NB][HID]; // depth-4 ring, 32KB
    __shared__ unsigned xbsm[NB * WPITCH];                      // 8.25KB bitwords
    __shared__ float gbuf[4][4][NB];                            // logit ring [s&3][wv][b]
    __shared__ float accb[4][NB];                               // per-L1-wave acc
    __shared__ int flag0[4], flag1[4];

    const int T  = threadIdx.x;
    const int w8 = T >> 6;
    const int Lw = w8 >> 2;       // 0: h0 convoy, 1: h1 convoy
    const int wv = w8 & 3;        // col quarter [32wv, +32)
    const int l  = T & 63, c = l & 15, g = l >> 4;
    const int bb0 = blockIdx.x * NB;
    const int swz = c << 3;

    // ---- pack x bits via ballot (coalesced) ----
    for (int idx = w8; idx < NB * (L_LEN / 64); idx += 8) {
        int batch = idx >> 6;
        int pos   = ((idx & 63) << 6) + l;
        int v     = x[(bb0 + batch) * L_LEN + pos];
        unsigned long long mask = __ballot(v & 1);
        if (l == 0)  xbsm[batch * WPITCH + ((idx & 63) << 1)]     = (unsigned)mask;
        if (l == 32) xbsm[batch * WPITCH + ((idx & 63) << 1) + 1] = (unsigned)(mask >> 32);
    }
    for (int i = T; i < 4 * 2 * NB * HID; i += TPB) ((unsigned short*)hAf)[i] = 0;
    if (T < 4) { flag0[T] = 0; flag1[T] = 0; }

    // ---- static A fragments: this wave's layer ----
    s16x8 Af[2][4];
    #pragma unroll
    for (int mt = 0; mt < 2; ++mt) {
        const int col = wv * 32 + mt * 16 + c;
        #pragma unroll
        for (int kt = 0; kt < 4; ++kt) {
            s16x8 f;
            #pragma unroll
            for (int j = 0; j < 8; ++j)
                f[j] = (short)f2bf(W_c[(Lw * HID + kt * 32 + g * 8 + j) * HID + col]);
            Af[mt][kt] = f;
        }
    }
    s16x8 woA;
    #pragma unroll
    for (int j = 0; j < 8; ++j)
        woA[j] = (c == 0) ? (short)f2bf(W_out[wv * 32 + g * 8 + j]) : (short)0;

    float R0v[2][4], R1v[2][4];
    #pragma unroll
    for (int mt = 0; mt < 2; ++mt)
      #pragma unroll
      for (int r = 0; r < 4; ++r) {
        int co = wv * 32 + mt * 16 + 4 * g + r;
        R0v[mt][r] = eluf(W_in[co]);
        R1v[mt][r] = eluf(W_in[HID + co]);
      }
    const float b0 = b_out[0];

    const int ro0 = (g * 8) ^ swz,      ro1 = (32 + g * 8) ^ swz;
    const int ro2 = (64 + g * 8) ^ swz, ro3 = (96 + g * 8) ^ swz;
    const int wo0 = (wv * 32 + 4 * g) ^ swz;
    const int wo1 = (wv * 32 + 16 + 4 * g) ^ swz;

    __syncthreads();   // the only block-wide barrier

    if (Lw == 0) {
        // ================= L0 convoy: h0[t], t = 1..4095 =================
        unsigned xw = 0;
        for (int t = 1; t < L_LEN; ++t) {
            wait_ge(flag0, wv, t - 1);      // peers done t-1
            wait_ge(flag1, -1, t - 3);      // ring backpressure (h0[t-4] dead)

            const unsigned short* hp = &hAf[(t - 1) & 3][0][c][0];
            s16x8 B0 = *(const s16x8*)&hp[ro0];
            s16x8 B1 = *(const s16x8*)&hp[ro1];
            s16x8 B2 = *(const s16x8*)&hp[ro2];
            s16x8 B3 = *(const s16x8*)&hp[ro3];
            if (((t - 1) & 31) == 0) xw = xbsm[c * WPITCH + ((t - 1) >> 5)];

            f32x4 CA = {0.f,0.f,0.f,0.f}, CB = {0.f,0.f,0.f,0.f};
            CA = MFMA16(Af[0][0], B0, CA); CA = MFMA16(Af[0][1], B1, CA);
            CA = MFMA16(Af[0][2], B2, CA); CA = MFMA16(Af[0][3], B3, CA);
            CB = MFMA16(Af[1][0], B0, CB); CB = MFMA16(Af[1][1], B1, CB);
            CB = MFMA16(Af[1][2], B2, CB); CB = MFMA16(Af[1][3], B3, CB);

            const int bit = (int)((xw >> ((t - 1) & 31)) & 1u);
            float ha0 = eluf(CA[0]) + (bit ? R1v[0][0] : R0v[0][0]);
            float ha1 = eluf(CA[1]) + (bit ? R1v[0][1] : R0v[0][1]);
            float ha2 = eluf(CA[2]) + (bit ? R1v[0][2] : R0v[0][2]);
            float ha3 = eluf(CA[3]) + (bit ? R1v[0][3] : R0v[0][3]);
            float hb0 = eluf(CB[0]) + (bit ? R1v[1][0] : R0v[1][0]);
            float hb1 = eluf(CB[1]) + (bit ? R1v[1][1] : R0v[1][1]);
            float hb2 = eluf(CB[2]) + (bit ? R1v[1][2] : R0v[1][2]);
            float hb3 = eluf(CB[3]) + (bit ? R1v[1][3] : R0v[1][3]);
            uint2 pa, pb;
            pa.x = cvtpk(ha0, ha1); pa.y = cvtpk(ha2, ha3);
            pb.x = cvtpk(hb0, hb1); pb.y = cvtpk(hb2, hb3);
            *(uint2*)&hAf[t & 3][0][c][wo0] = pa;
            *(uint2*)&hAf[t & 3][0][c][wo1] = pb;

            post(&flag0[wv], t);
        }
    } else {
        // ======== L1 convoy: h1[u] (u<=4095) + logit(h1[u-1]), u<=4096 ====
        float acc = 0.f;
        for (int u = 1; u <= L_LEN; ++u) {
            wait_ge(flag1, wv, u - 1);                       // peers done u-1
            wait_ge(flag0, -1, u < L_LEN ? u : L_LEN - 1);   // h0[u] ready

            const unsigned short* hp = &hAf[(u - 1) & 3][1][c][0];
            s16x8 B0 = *(const s16x8*)&hp[ro0];
            s16x8 B1 = *(const s16x8*)&hp[ro1];
            s16x8 B2 = *(const s16x8*)&hp[ro2];
            s16x8 B3 = *(const s16x8*)&hp[ro3];

            {   // logit partial for s = u-1, k-slice kt = wv
                s16x8 Bw = B0;
                if (wv == 1) Bw = B1; else if (wv == 2) Bw = B2;
                else if (wv == 3) Bw = B3;
                f32x4 Cg = {0.f,0.f,0.f,0.f};
                Cg = MFMA16(woA, Bw, Cg);
                if (g == 0) gbuf[(u - 1) & 3][wv][c] = Cg[0];
            }

            if (u < L_LEN) {   // h1[u] = elu(.) + h0[u]
                uint2 a0 = *(const uint2*)&hAf[u & 3][0][c][wo0];
                uint2 a1 = *(const uint2*)&hAf[u & 3][0][c][wo1];
                f32x4 CA = {0.f,0.f,0.f,0.f}, CB = {0.f,0.f,0.f,0.f};
                CA = MFMA16(Af[0][0], B0, CA); CA = MFMA16(Af[0][1], B1, CA);
                CA = MFMA16(Af[0][2], B2, CA); CA = MFMA16(Af[0][3], B3, CA);
                CB = MFMA16(Af[1][0], B0, CB); CB = MFMA16(Af[1][1], B1, CB);
                CB = MFMA16(Af[1][2], B2, CB); CB = MFMA16(Af[1][3], B3, CB);
                float ha0 = eluf(CA[0]) + __uint_as_float(a0.x << 16);
                float ha1 = eluf(CA[1]) + __uint_as_float(a0.x & 0xffff0000u);
                float ha2 = eluf(CA[2]) + __uint_as_float(a0.y << 16);
                float ha3 = eluf(CA[3]) + __uint_as_float(a0.y & 0xffff0000u);
                float hb0 = eluf(CB[0]) + __uint_as_float(a1.x << 16);
                float hb1 = eluf(CB[1]) + __uint_as_float(a1.x & 0xffff0000u);
                float hb2 = eluf(CB[2]) + __uint_as_float(a1.y << 16);
                float hb3 = eluf(CB[3]) + __uint_as_float(a1.y & 0xffff0000u);
                uint2 pa, pb;
                pa.x = cvtpk(ha0, ha1); pa.y = cvtpk(ha2, ha3);
                pb.x = cvtpk(hb0, hb1); pb.y = cvtpk(hb2, hb3);
                *(uint2*)&hAf[u & 3][1][c][wo0] = pa;
                *(uint2*)&hAf[u & 3][1][c][wo1] = pb;
            }

            post(&flag1[wv], u);

            // rotating consumer: s = u-2, handled by wave (s&3)
            int s_ = u - 2;
            if (s_ >= 0 && ((s_ & 3) == wv) && l < 16) {
                float gg = gbuf[s_ & 3][0][c] + gbuf[s_ & 3][1][c]
                         + gbuf[s_ & 3][2][c] + gbuf[s_ & 3][3][c] + b0;
                unsigned cw = xbsm[c * WPITCH + (s_ >> 5)];
                int bit = (cw >> (s_ & 31)) & 1;
                float mm  = fmaxf(gg, 0.f);
                float lse = mm + __logf(__expf(gg - mm) + __expf(-mm));
                acc += 0.5f * ((bit ? gg : 0.f) - lse);
            }
        }
        if (l < 16) accb[wv][c] = acc;
        post(&flag1[wv], L_LEN + 1);

        if (w8 == 7) {
            wait_ge(flag1, -1, L_LEN + 1);
            if (l < 16) {
                // tail s = 4095 (gbuf slot 3, written at u = 4096 by all)
                float gg = gbuf[3][0][c] + gbuf[3][1][c]
                         + gbuf[3][2][c] + gbuf[3][3][c] + b0;
                unsigned cw = xbsm[c * WPITCH + ((L_LEN - 1) >> 5)];
                int bit = (cw >> ((L_LEN - 1) & 31)) & 1;
                float mm  = fmaxf(gg, 0.f);
                float lse = mm + __logf(__expf(gg - mm) + __expf(-mm));
                float tail = 0.5f * ((bit ? gg : 0.f) - lse);
                out[bb0 + c] = accb[0][c] + accb[1][c] + accb[2][c]
                             + accb[3][c] + tail;
            }
        }
    }
}

extern "C" void kernel_launch(void* const* d_in, const int* in_sizes, int n_in,
                              void* d_out, int out_size, void* d_ws, size_t ws_size,
                              hipStream_t stream)
{
    const int*   x     = (const int*)  d_in[0];
    const float* W_in  = (const float*)d_in[1];
    const float* W_c   = (const float*)d_in[2];
    const float* W_out = (const float*)d_in[3];
    const float* b_out = (const float*)d_in[4];
    float* out = (float*)d_out;

    rnn_async_kernel<<<16, TPB, 0, stream>>>(x, W_in, W_c, W_out, b_out, out);
}